// Round 2
// baseline (5241.093 us; speedup 1.0000x reference)
//
#include <hip/hip_runtime.h>
#include <math.h>

#define T_STEPS 256
#define BATCH   4096
#define HID     64
#define MW      128
#define DOUT    8
#define RPB     8       // rows per block
#define NTH     256
#define ZP      68      // padded z-stash row stride (conflict-free readout)

__device__ __forceinline__ float fast_rcp(float x) { return __builtin_amdgcn_rcpf(x); }

__device__ __forceinline__ float lipswish(float x) {
    // 0.909 * x * sigmoid(x)
    float e = __expf(-x);
    return 0.909f * x * fast_rcp(1.0f + e);
}

__device__ __forceinline__ float fast_tanh(float x) {
    // tanh(x) = 1 - 2/(e^{2x}+1); saturates correctly for large |x|
    float e = __expf(2.0f * x);
    return 1.0f - 2.0f * fast_rcp(e + 1.0f);
}

__global__ __launch_bounds__(NTH, 2)
void sde_kernel(const float* __restrict__ ts,
                const float* __restrict__ dW,
                const float* __restrict__ dW0, const float* __restrict__ db0,
                const float* __restrict__ dW1, const float* __restrict__ db1,
                const float* __restrict__ dWo, const float* __restrict__ dbo,
                const float* __restrict__ gW0, const float* __restrict__ gb0,
                const float* __restrict__ gW1, const float* __restrict__ gb1,
                const float* __restrict__ gWo, const float* __restrict__ gbo,
                const float* __restrict__ rW,  const float* __restrict__ rb,
                float* __restrict__ out)
{
    // Activation tiles, [feature][row], row stride 8 (16B aligned, read as wave-uniform broadcasts)
    __shared__ __align__(16) float aT[65 * 8];        // MLP input (t, zhat)
    __shared__ __align__(16) float h1[2][MW * 8];     // layer-1 out  [mlp][j*8+r]
    __shared__ __align__(16) float h2[2][MW * 8];     // layer-2 out
    __shared__ float fb[2][RPB * HID];                // [0]=f, [1]=g   [r*64+j]
    __shared__ float zsb[2][RPB * ZP];                // double-buffered z stash
    __shared__ float rWs[HID * DOUT];
    __shared__ float rbs[DOUT];
    __shared__ float tsS[T_STEPS];

    const int tid = threadIdx.x;
    const int rowbase = blockIdx.x * RPB;

    for (int i = tid; i < HID * DOUT; i += NTH) rWs[i] = rW[i];
    if (tid < DOUT) rbs[tid] = rb[tid];
    for (int i = tid; i < T_STEPS; i += NTH) tsS[i] = ts[i];

    const float dt   = ts[1] - ts[0];
    const float sqdt = sqrtf(dt);

    // layer 1/2 role: neuron j12 (0..127), mlp m12; all 8 rows
    const int j12 = tid & 127;
    const int m12 = tid >> 7;
    // layer 3 role: neuron j3 (0..63), mlp m3, row-half rh3
    const int j3  = tid & 63;
    const int m3  = (tid >> 6) & 1;
    const int rh3 = tid >> 7;
    // update role: dim ud, rows uw*2, uw*2+1
    const int ud  = tid & 63;
    const int uw  = tid >> 6;
    const int r0  = uw * 2, r1 = uw * 2 + 1;

    const float* W0p = (m12 ? gW0 : dW0) + j12;    // stride MW
    const float* W1p = (m12 ? gW1 : dW1) + j12;    // stride MW
    const float* Wop = (m3  ? gWo : dWo) + j3;     // stride HID
    const float b0 = (m12 ? gb0 : db0)[j12];
    const float b1 = (m12 ? gb1 : db1)[j12];
    const float bo = (m3  ? gbo : dbo)[j3];

    // per-thread state for rows r0, r1
    float z0 = 1.0f, z1 = 1.0f, zh0 = 1.0f, zh1 = 1.0f;
    float f0r = 0.0f, f1r = 0.0f, g0r = 0.0f, g1r = 0.0f;
    float dw0 = 0.0f, dw1 = 0.0f;

    // ---- U(0): build aT for (t0, x0=ones); prefetch dW[0] ----
    aT[(1 + ud) * 8 + r0] = 1.0f;
    aT[(1 + ud) * 8 + r1] = 1.0f;
    if (ud == 0) { float t0 = ts[0]; aT[r0] = t0; aT[r1] = t0; }
    float dn0 = dW[(size_t)(rowbase + r0) * HID + ud];
    float dn1 = dW[(size_t)(rowbase + r1) * HID + ud];
    __syncthreads();

    for (int n = 1; n <= T_STEPS; ++n) {
        // ---------- Layer 1: 65 -> 128, fused drift+diff ----------
        {
            float acc[8];
            #pragma unroll
            for (int i = 0; i < 8; ++i) acc[i] = b0;
            #pragma unroll 8
            for (int k = 0; k < 65; ++k) {
                const float w = W0p[k * MW];
                const float4 a0 = *reinterpret_cast<const float4*>(&aT[k * 8]);
                const float4 a1 = *reinterpret_cast<const float4*>(&aT[k * 8 + 4]);
                acc[0] = fmaf(a0.x, w, acc[0]); acc[1] = fmaf(a0.y, w, acc[1]);
                acc[2] = fmaf(a0.z, w, acc[2]); acc[3] = fmaf(a0.w, w, acc[3]);
                acc[4] = fmaf(a1.x, w, acc[4]); acc[5] = fmaf(a1.y, w, acc[5]);
                acc[6] = fmaf(a1.z, w, acc[6]); acc[7] = fmaf(a1.w, w, acc[7]);
            }
            #pragma unroll
            for (int i = 0; i < 8; ++i) acc[i] = lipswish(acc[i]);
            *reinterpret_cast<float4*>(&h1[m12][j12 * 8])     = make_float4(acc[0], acc[1], acc[2], acc[3]);
            *reinterpret_cast<float4*>(&h1[m12][j12 * 8 + 4]) = make_float4(acc[4], acc[5], acc[6], acc[7]);
        }
        __syncthreads();

        // ---------- Layer 2: 128 -> 128 ----------
        {
            float acc[8];
            #pragma unroll
            for (int i = 0; i < 8; ++i) acc[i] = b1;
            const float* hin = h1[m12];
            #pragma unroll 8
            for (int k = 0; k < MW; ++k) {
                const float w = W1p[k * MW];
                const float4 a0 = *reinterpret_cast<const float4*>(&hin[k * 8]);
                const float4 a1 = *reinterpret_cast<const float4*>(&hin[k * 8 + 4]);
                acc[0] = fmaf(a0.x, w, acc[0]); acc[1] = fmaf(a0.y, w, acc[1]);
                acc[2] = fmaf(a0.z, w, acc[2]); acc[3] = fmaf(a0.w, w, acc[3]);
                acc[4] = fmaf(a1.x, w, acc[4]); acc[5] = fmaf(a1.y, w, acc[5]);
                acc[6] = fmaf(a1.z, w, acc[6]); acc[7] = fmaf(a1.w, w, acc[7]);
            }
            #pragma unroll
            for (int i = 0; i < 8; ++i) acc[i] = lipswish(acc[i]);
            *reinterpret_cast<float4*>(&h2[m12][j12 * 8])     = make_float4(acc[0], acc[1], acc[2], acc[3]);
            *reinterpret_cast<float4*>(&h2[m12][j12 * 8 + 4]) = make_float4(acc[4], acc[5], acc[6], acc[7]);
        }
        __syncthreads();

        // ---------- Layer 3: 128 -> 64, tanh ----------
        {
            float acc[4];
            #pragma unroll
            for (int i = 0; i < 4; ++i) acc[i] = bo;
            const float* hin = h2[m3];
            #pragma unroll 8
            for (int k = 0; k < MW; ++k) {
                const float w = Wop[k * HID];
                const float4 a = *reinterpret_cast<const float4*>(&hin[k * 8 + rh3 * 4]);
                acc[0] = fmaf(a.x, w, acc[0]); acc[1] = fmaf(a.y, w, acc[1]);
                acc[2] = fmaf(a.z, w, acc[2]); acc[3] = fmaf(a.w, w, acc[3]);
            }
            #pragma unroll
            for (int i = 0; i < 4; ++i)
                fb[m3][(rh3 * 4 + i) * HID + j3] = fast_tanh(acc[i]);
        }
        __syncthreads();

        // ---------- U(n): finish z_{n-1}, stash, readout row n-2, build aT(t_n) ----------
        {
            const float fn0 = fb[0][r0 * HID + ud], gn0 = fb[1][r0 * HID + ud];
            const float fn1 = fb[0][r1 * HID + ud], gn1 = fb[1][r1 * HID + ud];
            if (n > 1) {
                z0 += 0.5f * (f0r + fn0) * dt + 0.5f * (g0r + gn0) * dw0;
                z1 += 0.5f * (f1r + fn1) * dt + 0.5f * (g1r + gn1) * dw1;
            }
            const int p = n & 1;
            zsb[p][r0 * ZP + ud] = z0;
            zsb[p][r1 * ZP + ud] = z1;

            if (n < T_STEPS) {
                // consume prefetched dW -> dw_n ; prefetch dW[n]
                dw0 = dn0 * sqdt; dw1 = dn1 * sqdt;
                const int np = (n < T_STEPS - 2) ? n : (T_STEPS - 2);
                dn0 = dW[(size_t)np * (BATCH * HID) + (size_t)(rowbase + r0) * HID + ud];
                dn1 = dW[(size_t)np * (BATCH * HID) + (size_t)(rowbase + r1) * HID + ud];
                // zhat_n = 2 z_{n-1} - zhat_{n-1} + f_{n-1} dt + g_{n-1} dw_n
                zh0 = 2.0f * z0 - zh0 + fn0 * dt + gn0 * dw0;
                zh1 = 2.0f * z1 - zh1 + fn1 * dt + gn1 * dw1;
                aT[(1 + ud) * 8 + r0] = zh0;
                aT[(1 + ud) * 8 + r1] = zh1;
                if (ud == 0) { const float tn = tsS[n]; aT[r0] = tn; aT[r1] = tn; }
            }
            f0r = fn0; g0r = gn0; f1r = fn1; g1r = gn1;

            // readout of z_{n-2} (stable buffer written at U(n-1))
            if (n >= 2 && tid < 64) {
                const int r = tid >> 3, d = tid & 7;
                const int q = (n - 1) & 1;
                float acc = rbs[d];
                #pragma unroll 8
                for (int k = 0; k < HID; ++k)
                    acc = fmaf(zsb[q][r * ZP + k], rWs[k * DOUT + d], acc);
                float* op = out + (size_t)(rowbase + r) * (T_STEPS * (DOUT + 1))
                                + (size_t)(n - 2) * (DOUT + 1);
                op[1 + d] = acc;
                if (d == 0) op[0] = tsS[n - 2];
            }
        }
        __syncthreads();
    }

    // ---------- epilogue: readout rows 254 (z_254) and 255 (z_255) ----------
    // z_255 was completed and stashed at U(256) into zsb[0]; z_254 is in zsb[1].
    if (tid < 64) {
        const int r = tid >> 3, d = tid & 7;
        float* obase = out + (size_t)(rowbase + r) * (T_STEPS * (DOUT + 1));
        {
            float acc = rbs[d];
            #pragma unroll 8
            for (int k = 0; k < HID; ++k)
                acc = fmaf(zsb[1][r * ZP + k], rWs[k * DOUT + d], acc);
            float* op = obase + (size_t)(T_STEPS - 2) * (DOUT + 1);
            op[1 + d] = acc;
            if (d == 0) op[0] = tsS[T_STEPS - 2];
        }
        {
            float acc = rbs[d];
            #pragma unroll 8
            for (int k = 0; k < HID; ++k)
                acc = fmaf(zsb[0][r * ZP + k], rWs[k * DOUT + d], acc);
            float* op = obase + (size_t)(T_STEPS - 1) * (DOUT + 1);
            op[1 + d] = acc;
            if (d == 0) op[0] = tsS[T_STEPS - 1];
        }
    }
}

extern "C" void kernel_launch(void* const* d_in, const int* in_sizes, int n_in,
                              void* d_out, int out_size, void* d_ws, size_t ws_size,
                              hipStream_t stream) {
    const float* ts  = (const float*)d_in[0];
    const float* dW  = (const float*)d_in[2];
    const float* dW0 = (const float*)d_in[3];
    const float* db0 = (const float*)d_in[4];
    const float* dW1 = (const float*)d_in[5];
    const float* db1 = (const float*)d_in[6];
    const float* dWo = (const float*)d_in[7];
    const float* dbo = (const float*)d_in[8];
    const float* gW0 = (const float*)d_in[9];
    const float* gb0 = (const float*)d_in[10];
    const float* gW1 = (const float*)d_in[11];
    const float* gb1 = (const float*)d_in[12];
    const float* gWo = (const float*)d_in[13];
    const float* gbo = (const float*)d_in[14];
    const float* rW  = (const float*)d_in[15];
    const float* rb  = (const float*)d_in[16];
    float* out = (float*)d_out;

    sde_kernel<<<dim3(BATCH / RPB), dim3(NTH), 0, stream>>>(
        ts, dW, dW0, db0, dW1, db1, dWo, dbo,
        gW0, gb0, gW1, gb1, gWo, gbo, rW, rb, out);
}

// Round 3
// 890.065 us; speedup vs baseline: 5.8884x; 5.8884x over previous
//
#include <hip/hip_runtime.h>
#include <math.h>

#define T_STEPS 256
#define BATCH   4096
#define HID     64
#define MW      128
#define DOUT    8
#define RPB     16
#define NTH     256
#define AS      72    // Ain/zb row stride in halfs (144B: 16B-aligned, 2-way banks)
#define HS      136   // h1/h2 row stride in halfs (272B: 16B-aligned, 2-way banks)

typedef _Float16 half8 __attribute__((ext_vector_type(8)));
typedef float    f32x4 __attribute__((ext_vector_type(4)));

__device__ __forceinline__ float fast_rcp(float x) { return __builtin_amdgcn_rcpf(x); }
__device__ __forceinline__ float lipswish(float x) {
    float e = __expf(-x);
    return 0.909f * x * fast_rcp(1.0f + e);
}
__device__ __forceinline__ float fast_tanh(float x) {
    float e = __expf(2.0f * x);
    return 1.0f - 2.0f * fast_rcp(e + 1.0f);
}

#define MFMA(a, b, c) __builtin_amdgcn_mfma_f32_16x16x32_f16((a), (b), (c), 0, 0, 0)

// MFMA 16x16x32 layout conventions (gfx950, guide-verified):
//   A[m][k]: m = lane&15, k = (lane>>4)*8 + j   (8 halfs, K-contiguous)
//   B[k][n]: n = lane&15, k = (lane>>4)*8 + j
//   C/D   : col n = lane&15, row m = (lane>>4)*4 + reg

__global__ __launch_bounds__(NTH, 1)
void sde_kernel(const float* __restrict__ ts,
                const float* __restrict__ dW,
                const float* __restrict__ dW0, const float* __restrict__ db0,
                const float* __restrict__ dW1, const float* __restrict__ db1,
                const float* __restrict__ dWo, const float* __restrict__ dbo,
                const float* __restrict__ gW0, const float* __restrict__ gb0,
                const float* __restrict__ gW1, const float* __restrict__ gb1,
                const float* __restrict__ gWo, const float* __restrict__ gbo,
                const float* __restrict__ rW,  const float* __restrict__ rb,
                float* __restrict__ out)
{
    __shared__ _Float16 Ain_hi[RPB][AS];   // L1 input (t-folded), hi part
    __shared__ _Float16 Ain_lo[RPB][AS];   // L1 input, lo part (fp32-exact split)
    __shared__ _Float16 h1b[2][RPB][HS];   // layer-1 out per mlp
    __shared__ _Float16 h2b[2][RPB][HS];   // layer-2 out per mlp
    __shared__ _Float16 zb[2][RPB][AS];    // z stash (f16) for MFMA readout
    __shared__ _Float16 fgb[2][RPB][HID];  // [0]=f, [1]=g
    __shared__ float    bias1t[2 * MW];    // per-step L1 bias incl. t * W0row0
    __shared__ float    tsS[T_STEPS];

    const int tid  = threadIdx.x;
    const int lane = tid & 63;
    const int wid  = tid >> 6;
    const int l15  = lane & 15;
    const int quad = lane >> 4;
    const int mlp  = wid >> 1;     // 0 = drift, 1 = diff
    const int nh   = wid & 1;      // neuron half
    const int rowbase = blockIdx.x * RPB;

    for (int i = tid; i < T_STEPS; i += NTH) tsS[i] = ts[i];

    const float t0   = ts[0];
    const float dt   = ts[1] - t0;
    const float sqdt = sqrtf(dt);

    // ---------------- static weight fragments in VGPRs ----------------
    const float* W0 = mlp ? gW0 : dW0;   // (65,128); row 0 = t weights
    const float* W1 = mlp ? gW1 : dW1;   // (128,128)
    const float* Wo = mlp ? gWo : dWo;   // (128,64)

    half8 bw1[2][4], bw2[4][4], bw3[4][2];
    #pragma unroll
    for (int kt = 0; kt < 2; ++kt)
        #pragma unroll
        for (int nt = 0; nt < 4; ++nt) {
            half8 v;
            #pragma unroll
            for (int j = 0; j < 8; ++j) {
                const int k = kt * 32 + quad * 8 + j;
                const int n = nh * 64 + nt * 16 + l15;
                v[j] = (_Float16)W0[(1 + k) * MW + n];
            }
            bw1[kt][nt] = v;
        }
    #pragma unroll
    for (int kt = 0; kt < 4; ++kt)
        #pragma unroll
        for (int nt = 0; nt < 4; ++nt) {
            half8 v;
            #pragma unroll
            for (int j = 0; j < 8; ++j) {
                const int k = kt * 32 + quad * 8 + j;
                const int n = nh * 64 + nt * 16 + l15;
                v[j] = (_Float16)W1[k * MW + n];
            }
            bw2[kt][nt] = v;
        }
    #pragma unroll
    for (int kt = 0; kt < 4; ++kt)
        #pragma unroll
        for (int nt = 0; nt < 2; ++nt) {
            half8 v;
            #pragma unroll
            for (int j = 0; j < 8; ++j) {
                const int k = kt * 32 + quad * 8 + j;
                const int n = nh * 32 + nt * 16 + l15;
                v[j] = (_Float16)Wo[k * HID + n];
            }
            bw3[kt][nt] = v;
        }

    float b2v[4], b3v[2];
    {
        const float* b1p = mlp ? gb1 : db1;
        const float* bop = mlp ? gbo : dbo;
        #pragma unroll
        for (int nt = 0; nt < 4; ++nt) b2v[nt] = b1p[nh * 64 + nt * 16 + l15];
        #pragma unroll
        for (int nt = 0; nt < 2; ++nt) b3v[nt] = bop[nh * 32 + nt * 16 + l15];
    }

    // readout fragments (wave 0 only)
    half8 brd[2];
    float rbv = 0.0f;
    int   ocol = 0;
    if (wid == 0) {
        #pragma unroll
        for (int kt = 0; kt < 2; ++kt) {
            half8 v;
            #pragma unroll
            for (int j = 0; j < 8; ++j) {
                const int k = kt * 32 + quad * 8 + j;
                v[j] = (l15 < 8) ? (_Float16)rW[k * DOUT + l15] : (_Float16)0.0f;
            }
            brd[kt] = v;
        }
        rbv  = (l15 < 8) ? rb[l15] : 0.0f;
        ocol = (l15 == 8) ? 0 : (l15 + 1);
    }

    // per-thread statics for the t-folded L1 bias (thread -> (mlp, neuron))
    const float b0s = (tid < 128 ? db0 : gb0)[tid & 127];
    const float w0s = (tid < 128 ? dW0 : gW0)[tid & 127];  // W0 row 0

    // ---------------- state registers (update mapping: dim=lane, rows wid+4i) ----
    const int ud = lane;
    float z[4], zh[4], fold[4], gold[4], dwr[4], dn[4];
    #pragma unroll
    for (int i = 0; i < 4; ++i) { z[i] = 1.0f; zh[i] = 1.0f; dwr[i] = 0.0f; }

    // ---- pre-loop: Ain <- (x0 = ones), bias1t(t0), prefetch dW[0] ----
    #pragma unroll
    for (int i = 0; i < 4; ++i) {
        const int r = wid + 4 * i;
        Ain_hi[r][ud] = (_Float16)1.0f;
        Ain_lo[r][ud] = (_Float16)0.0f;
        dn[i] = dW[(size_t)(rowbase + r) * HID + ud];
    }
    bias1t[tid] = b0s + t0 * w0s;
    __syncthreads();

    for (int n = 1; n <= T_STEPS; ++n) {
        // ================= Layer 1: 64 -> 128 (split-A, 2 mfma/tile) ===========
        {
            const int koff = quad * 8;
            half8 ah[2], al[2];
            #pragma unroll
            for (int kt = 0; kt < 2; ++kt) {
                ah[kt] = *(const half8*)&Ain_hi[l15][kt * 32 + koff];
                al[kt] = *(const half8*)&Ain_lo[l15][kt * 32 + koff];
            }
            f32x4 acc[4];
            #pragma unroll
            for (int nt = 0; nt < 4; ++nt) {
                const float b = bias1t[mlp * MW + nh * 64 + nt * 16 + l15];
                acc[nt] = (f32x4){b, b, b, b};
            }
            #pragma unroll
            for (int nt = 0; nt < 4; ++nt)
                #pragma unroll
                for (int kt = 0; kt < 2; ++kt) {
                    acc[nt] = MFMA(ah[kt], bw1[kt][nt], acc[nt]);
                    acc[nt] = MFMA(al[kt], bw1[kt][nt], acc[nt]);
                }
            #pragma unroll
            for (int nt = 0; nt < 4; ++nt)
                #pragma unroll
                for (int i2 = 0; i2 < 4; ++i2) {
                    const float v = lipswish(acc[nt][i2]);
                    h1b[mlp][quad * 4 + i2][nh * 64 + nt * 16 + l15] = (_Float16)v;
                }

            // -------- readout of z_{n-2} via MFMA (wave 0) --------
            if (wid == 0 && n >= 2) {
                const int q = (n - 1) & 1, s = n - 2;
                half8 a0 = *(const half8*)&zb[q][l15][koff];
                half8 a1 = *(const half8*)&zb[q][l15][32 + koff];
                f32x4 racc = (f32x4){rbv, rbv, rbv, rbv};
                racc = MFMA(a0, brd[0], racc);
                racc = MFMA(a1, brd[1], racc);
                if (l15 < 9) {
                    const float tv = tsS[s];
                    #pragma unroll
                    for (int i2 = 0; i2 < 4; ++i2) {
                        const int r = quad * 4 + i2;
                        out[(size_t)(rowbase + r) * (T_STEPS * 9) + s * 9 + ocol]
                            = (l15 < 8) ? racc[i2] : tv;
                    }
                }
            }
        }
        __syncthreads();

        // ================= Layer 2: 128 -> 128 =================
        {
            half8 a[4];
            #pragma unroll
            for (int kt = 0; kt < 4; ++kt)
                a[kt] = *(const half8*)&h1b[mlp][l15][kt * 32 + quad * 8];
            f32x4 acc[4];
            #pragma unroll
            for (int nt = 0; nt < 4; ++nt)
                acc[nt] = (f32x4){b2v[nt], b2v[nt], b2v[nt], b2v[nt]};
            #pragma unroll
            for (int nt = 0; nt < 4; ++nt)
                #pragma unroll
                for (int kt = 0; kt < 4; ++kt)
                    acc[nt] = MFMA(a[kt], bw2[kt][nt], acc[nt]);
            #pragma unroll
            for (int nt = 0; nt < 4; ++nt)
                #pragma unroll
                for (int i2 = 0; i2 < 4; ++i2) {
                    const float v = lipswish(acc[nt][i2]);
                    h2b[mlp][quad * 4 + i2][nh * 64 + nt * 16 + l15] = (_Float16)v;
                }
        }
        __syncthreads();

        // ================= Layer 3: 128 -> 64, tanh =================
        {
            half8 a[4];
            #pragma unroll
            for (int kt = 0; kt < 4; ++kt)
                a[kt] = *(const half8*)&h2b[mlp][l15][kt * 32 + quad * 8];
            f32x4 acc[2];
            #pragma unroll
            for (int nt = 0; nt < 2; ++nt)
                acc[nt] = (f32x4){b3v[nt], b3v[nt], b3v[nt], b3v[nt]};
            #pragma unroll
            for (int nt = 0; nt < 2; ++nt)
                #pragma unroll
                for (int kt = 0; kt < 4; ++kt)
                    acc[nt] = MFMA(a[kt], bw3[kt][nt], acc[nt]);
            #pragma unroll
            for (int nt = 0; nt < 2; ++nt)
                #pragma unroll
                for (int i2 = 0; i2 < 4; ++i2)
                    fgb[mlp][quad * 4 + i2][nh * 32 + nt * 16 + l15]
                        = (_Float16)fast_tanh(acc[nt][i2]);
        }
        __syncthreads();

        // ================= Update phase =================
        {
            float fn[4], gn[4];
            #pragma unroll
            for (int i = 0; i < 4; ++i) {
                const int r = wid + 4 * i;
                fn[i] = (float)fgb[0][r][ud];
                gn[i] = (float)fgb[1][r][ud];
            }
            if (n > 1) {
                #pragma unroll
                for (int i = 0; i < 4; ++i)
                    z[i] += 0.5f * (fold[i] + fn[i]) * dt + 0.5f * (gold[i] + gn[i]) * dwr[i];
            }
            const int p = n & 1;
            #pragma unroll
            for (int i = 0; i < 4; ++i)
                zb[p][wid + 4 * i][ud] = (_Float16)z[i];

            if (n < T_STEPS) {
                const int np = (n < T_STEPS - 2) ? n : (T_STEPS - 2);
                #pragma unroll
                for (int i = 0; i < 4; ++i) {
                    const int r = wid + 4 * i;
                    dwr[i] = dn[i] * sqdt;
                    dn[i]  = dW[(size_t)np * (BATCH * HID) + (size_t)(rowbase + r) * HID + ud];
                    zh[i]  = 2.0f * z[i] - zh[i] + fn[i] * dt + gn[i] * dwr[i];
                    const _Float16 hi = (_Float16)zh[i];
                    Ain_hi[r][ud] = hi;
                    Ain_lo[r][ud] = (_Float16)(zh[i] - (float)hi);
                }
                bias1t[tid] = b0s + tsS[n] * w0s;
            }
            #pragma unroll
            for (int i = 0; i < 4; ++i) { fold[i] = fn[i]; gold[i] = gn[i]; }
        }
        __syncthreads();
    }

    // ---- epilogue: readout of z_255 (stashed in zb[0] at U(256)) ----
    if (wid == 0) {
        const int koff = quad * 8, s = T_STEPS - 1;
        half8 a0 = *(const half8*)&zb[0][l15][koff];
        half8 a1 = *(const half8*)&zb[0][l15][32 + koff];
        f32x4 racc = (f32x4){rbv, rbv, rbv, rbv};
        racc = MFMA(a0, brd[0], racc);
        racc = MFMA(a1, brd[1], racc);
        if (l15 < 9) {
            const float tv = tsS[s];
            #pragma unroll
            for (int i2 = 0; i2 < 4; ++i2) {
                const int r = quad * 4 + i2;
                out[(size_t)(rowbase + r) * (T_STEPS * 9) + s * 9 + ocol]
                    = (l15 < 8) ? racc[i2] : tv;
            }
        }
    }
}

extern "C" void kernel_launch(void* const* d_in, const int* in_sizes, int n_in,
                              void* d_out, int out_size, void* d_ws, size_t ws_size,
                              hipStream_t stream) {
    const float* ts  = (const float*)d_in[0];
    const float* dW  = (const float*)d_in[2];
    const float* dW0 = (const float*)d_in[3];
    const float* db0 = (const float*)d_in[4];
    const float* dW1 = (const float*)d_in[5];
    const float* db1 = (const float*)d_in[6];
    const float* dWo = (const float*)d_in[7];
    const float* dbo = (const float*)d_in[8];
    const float* gW0 = (const float*)d_in[9];
    const float* gb0 = (const float*)d_in[10];
    const float* gW1 = (const float*)d_in[11];
    const float* gb1 = (const float*)d_in[12];
    const float* gWo = (const float*)d_in[13];
    const float* gbo = (const float*)d_in[14];
    const float* rW  = (const float*)d_in[15];
    const float* rb  = (const float*)d_in[16];
    float* out = (float*)d_out;

    sde_kernel<<<dim3(BATCH / RPB), dim3(NTH), 0, stream>>>(
        ts, dW, dW0, db0, dW1, db1, dWo, dbo,
        gW0, gb0, gW1, gb1, gWo, gbo, rW, rb, out);
}